// Round 15
// baseline (10015.717 us; speedup 1.0000x reference)
//
#include <hip/hip_runtime.h>

#define SEQ 2048
#define DM  1024
#define NH  16
#define HDIM 64

typedef __bf16 bf16x8 __attribute__((ext_vector_type(8)));

// ---------------------------------------------------------------- decay LUT
__global__ void decay_kernel(float* __restrict__ lut) {
    int i = blockIdx.x * 256 + threadIdx.x;
    if (i < SEQ) lut[i] = expf(-0.1f * (float)i);
}

// ------------------------------------------------ sentinel: zero the output
__global__ void zero_out(float* __restrict__ out, int n) {
    int i = blockIdx.x * 256 + threadIdx.x;
    if (i < n) out[i] = 0.f;
}

// ---------------------------------- naive projection, fp32 out (q,k,eq,ek)
__global__ __launch_bounds__(256) void proj_f32(
    const float* __restrict__ hs, const float* __restrict__ W,
    const float* __restrict__ B, float* __restrict__ Out)
{
    const int s = blockIdx.x;
    __shared__ float hrow[DM];
    for (int i = threadIdx.x; i < DM; i += 256)
        hrow[i] = hs[(size_t)s * DM + i];
    __syncthreads();
    for (int c = threadIdx.x; c < DM; c += 256) {
        const float* wr = W + (size_t)c * DM;
        float acc = B[c];
        for (int k = 0; k < DM; ++k) acc += hrow[k] * wr[k];
        Out[(size_t)s * DM + c] = acc;
    }
}

// ---------------------------------- naive projection, bf16 out (v only)
__global__ __launch_bounds__(256) void proj_bf(
    const float* __restrict__ hs, const float* __restrict__ W,
    const float* __restrict__ B, __bf16* __restrict__ Out)
{
    const int s = blockIdx.x;
    __shared__ float hrow[DM];
    for (int i = threadIdx.x; i < DM; i += 256)
        hrow[i] = hs[(size_t)s * DM + i];
    __syncthreads();
    for (int c = threadIdx.x; c < DM; c += 256) {
        const float* wr = W + (size_t)c * DM;
        float acc = B[c];
        for (int k = 0; k < DM; ++k) acc += hrow[k] * wr[k];
        Out[(size_t)s * DM + c] = (__bf16)acc;
    }
}

// ------------------------------------- out-proj + residual (fp32)
__global__ __launch_bounds__(256) void outproj_naive(
    const __bf16* __restrict__ ctx, const float* __restrict__ Wo,
    const float* __restrict__ bo, const float* __restrict__ hs,
    float* __restrict__ res)
{
    const int s = blockIdx.x;
    __shared__ float crow[DM];
    for (int i = threadIdx.x; i < DM; i += 256)
        crow[i] = (float)ctx[(size_t)s * DM + i];
    __syncthreads();
    for (int c = threadIdx.x; c < DM; c += 256) {
        const float* wr = Wo + (size_t)c * DM;
        float acc = bo[c];
        for (int k = 0; k < DM; ++k) acc += crow[k] * wr[k];
        res[(size_t)s * DM + c] = acc + hs[(size_t)s * DM + c];
    }
}

// ------------------------------------- naive amplitudes / phases (fp32)
__global__ __launch_bounds__(256) void amp_naive(
    const float* __restrict__ hs,
    const float* __restrict__ amp_w, const float* __restrict__ amp_b,
    const float* __restrict__ ph_w,  const float* __restrict__ ph_b,
    float* __restrict__ cA, float* __restrict__ sA)
{
    const int s = blockIdx.x;
    __shared__ float hrow[DM];
    for (int i = threadIdx.x; i < DM; i += 256)
        hrow[i] = hs[(size_t)s * DM + i];
    __syncthreads();
    if (threadIdx.x < NH) {
        const int h = threadIdx.x;
        float da = amp_b[h], dp = ph_b[h];
        for (int k = 0; k < DM; ++k) {
            da += hrow[k] * amp_w[(size_t)h * DM + k];
            dp += hrow[k] * ph_w[(size_t)h * DM + k];
        }
        float amp = 1.f / (1.f + expf(-da));
        float ph  = tanhf(dp) * 3.14159265358979323846f;
        cA[s * NH + h] = 0.3f * amp * cosf(ph);
        sA[s * NH + h] = 0.3f * amp * sinf(ph);
    }
}

// ------------------------------------- naive mixer -> mixedT[h*64+o][s]
__global__ __launch_bounds__(64) void mixer_naive(
    const __bf16* __restrict__ v, const float* __restrict__ mix_w,
    const float* __restrict__ mix_b,
    const float* __restrict__ cA, const float* __restrict__ sA,
    __bf16* __restrict__ mixedT)
{
    const int s = blockIdx.x, h = blockIdx.y, o = threadIdx.x;  // 64 threads
    __shared__ float vrow[HDIM], sup[HDIM];
    vrow[o] = (float)v[(size_t)s * DM + h * HDIM + o];
    __syncthreads();
    float acc = mix_b[h * HDIM + o];
    const float* wr = mix_w + (size_t)h * HDIM * HDIM + o * HDIM;
    for (int d = 0; d < HDIM; ++d) acc += vrow[d] * wr[d];
    sup[o] = acc;
    __syncthreads();
    const float ca = cA[s * NH + h], sa = sA[s * NH + h];
    const float mval = vrow[o] + ca * sup[o] + sa * sup[(o + 63) & 63];
    mixedT[(size_t)(h * HDIM + o) * SEQ + s] = (__bf16)mval;
}

// ------------------- brute-force attention, fp32 q/k/eq/ek (block (s,h))
__global__ __launch_bounds__(256) void attn_f32(
    const float* __restrict__ q, const float* __restrict__ k,
    const float* __restrict__ eq, const float* __restrict__ ek,
    const __bf16* __restrict__ mixedT, const float* __restrict__ lutg,
    __bf16* __restrict__ ctx)
{
    const int s = blockIdx.x, h = blockIdx.y;
    const int tid = threadIdx.x, wave = tid >> 6, lane = tid & 63;

    __shared__ float logit[SEQ];
    __shared__ float qrow[HDIM], eqrow[HDIM];
    __shared__ float red[8];
    __shared__ float part[4][HDIM];

    if (tid < 64)       qrow[tid]       = q [(size_t)s * DM + h * HDIM + tid];
    else if (tid < 128) eqrow[tid - 64] = eq[(size_t)s * DM + h * HDIM + tid - 64];
    __syncthreads();

    float lm = -1e30f;
    for (int key = tid; key < SEQ; key += 256) {
        const float4* kr = reinterpret_cast<const float4*>(k  + (size_t)key * DM + h * HDIM);
        const float4* er = reinterpret_cast<const float4*>(ek + (size_t)key * DM + h * HDIM);
        float dq = 0.f, de = 0.f;
#pragma unroll
        for (int i = 0; i < 16; ++i) {
            float4 kv = kr[i], ev = er[i];
            dq += qrow[4*i] * kv.x + qrow[4*i+1] * kv.y
                + qrow[4*i+2] * kv.z + qrow[4*i+3] * kv.w;
            de += eqrow[4*i] * ev.x + eqrow[4*i+1] * ev.y
                + eqrow[4*i+2] * ev.z + eqrow[4*i+3] * ev.w;
        }
        int dd = s - key; dd = dd < 0 ? -dd : dd;
        float lg = 0.125f * dq + 0.0625f * de * lutg[dd];
        logit[key] = lg;
        lm = fmaxf(lm, lg);
    }
#pragma unroll
    for (int off = 32; off >= 1; off >>= 1) lm = fmaxf(lm, __shfl_xor(lm, off));
    if (lane == 0) red[wave] = lm;
    __syncthreads();
    const float mx = fmaxf(fmaxf(red[0], red[1]), fmaxf(red[2], red[3]));

    float ls = 0.f;
    for (int key = tid; key < SEQ; key += 256) {
        float p = expf(logit[key] - mx);
        logit[key] = p;
        ls += p;
    }
#pragma unroll
    for (int off = 32; off >= 1; off >>= 1) ls += __shfl_xor(ls, off);
    if (lane == 0) red[4 + wave] = ls;
    __syncthreads();
    const float denom = red[4] + red[5] + red[6] + red[7];

    const int d = tid & 63, g = tid >> 6;
    const __bf16* mrow = mixedT + (size_t)(h * HDIM + d) * SEQ;
    float acc = 0.f;
    for (int key = g * 512; key < (g + 1) * 512; key += 8) {
        bf16x8 mv = *reinterpret_cast<const bf16x8*>(mrow + key);
#pragma unroll
        for (int e = 0; e < 8; ++e) acc += logit[key + e] * (float)mv[e];
    }
    part[g][d] = acc;
    __syncthreads();
    if (tid < 64) {
        float val = (part[0][tid] + part[1][tid] + part[2][tid] + part[3][tid]) / denom;
        ctx[(size_t)s * DM + h * HDIM + tid] = (__bf16)val;
    }
}

// --------------------------------------------- layer norm, FP32 OUTPUT
__global__ __launch_bounds__(256) void lnorm_f32(
    const float* __restrict__ res, const float* __restrict__ g,
    const float* __restrict__ b, float* __restrict__ out)
{
    const int row = blockIdx.x, tid = threadIdx.x;
    const int wave = tid >> 6, lane = tid & 63;
    __shared__ float red[8];
    const float4 x = reinterpret_cast<const float4*>(res + (size_t)row * DM)[tid];
    float s  = x.x + x.y + x.z + x.w;
    float s2 = x.x * x.x + x.y * x.y + x.z * x.z + x.w * x.w;
#pragma unroll
    for (int off = 32; off >= 1; off >>= 1) {
        s  += __shfl_xor(s, off);
        s2 += __shfl_xor(s2, off);
    }
    if (lane == 0) { red[wave] = s; red[4 + wave] = s2; }
    __syncthreads();
    s  = red[0] + red[1] + red[2] + red[3];
    s2 = red[4] + red[5] + red[6] + red[7];
    const float mu  = s * (1.f / DM);
    const float var = s2 * (1.f / DM) - mu * mu;
    const float inv = rsqrtf(var + 1e-5f);
    const int col = tid * 4;
    float4 o;
    o.x = (x.x - mu) * inv * g[col + 0] + b[col + 0];
    o.y = (x.y - mu) * inv * g[col + 1] + b[col + 1];
    o.z = (x.z - mu) * inv * g[col + 2] + b[col + 2];
    o.w = (x.w - mu) * inv * g[col + 3] + b[col + 3];
    reinterpret_cast<float4*>(out + (size_t)row * DM)[tid] = o;
}

// ---------------------------------------------------------------- launch
// OUTPUT IS FP32 (the "(bf16)" in the harness error label is hard-coded
// f-string text, not the executed dtype branch — 12 rounds of decorrelated
// errors were my bf16 4MB written into an 8MB fp32 buffer: the fp32 read
// re-interprets element pairs => positional scramble => err ~ sqrt(2)*max).
// Values: r8's faithful pipeline (scaled attention, residual included,
// fp32 critical path). ws ~36.3 MB as r8. vb/ctx staged bf16 in d_out
// (dead before lnorm_f32 rewrites the full 8MB).
extern "C" void kernel_launch(void* const* d_in, const int* in_sizes, int n_in,
                              void* d_out, int out_size, void* d_ws, size_t ws_size,
                              hipStream_t stream) {
    const float* hs   = (const float*)d_in[0];
    const float* Wq   = (const float*)d_in[1];
    const float* bq   = (const float*)d_in[2];
    const float* Wk   = (const float*)d_in[3];
    const float* bk   = (const float*)d_in[4];
    const float* Wv   = (const float*)d_in[5];
    const float* bv   = (const float*)d_in[6];
    const float* Wo   = (const float*)d_in[7];
    const float* bo   = (const float*)d_in[8];
    const float* Weq  = (const float*)d_in[9];
    const float* beq  = (const float*)d_in[10];
    const float* Wek  = (const float*)d_in[11];
    const float* bek  = (const float*)d_in[12];
    const float* ampw = (const float*)d_in[13];
    const float* ampb = (const float*)d_in[14];
    const float* phw  = (const float*)d_in[15];
    const float* phb  = (const float*)d_in[16];
    const float* mixw = (const float*)d_in[17];
    const float* mixb = (const float*)d_in[18];
    const float* lng  = (const float*)d_in[19];
    const float* lnb  = (const float*)d_in[20];
    float* out = (float*)d_out;

    static const int expect[21] = {
        2097152, 1048576, 1024, 1048576, 1024, 1048576, 1024, 1048576, 1024,
        1048576, 1024, 1048576, 1024, 16384, 16, 16384, 16, 65536, 1024,
        1024, 1024};
    bool ok = (n_in == 21) && (out_size == 2097152);
    if (ok) for (int i = 0; i < 21; ++i) ok = ok && (in_sizes[i] == expect[i]);
    if (!ok) {
        zero_out<<<(out_size + 255) / 256, 256, 0, stream>>>(out, out_size);
        return;
    }

    char* ws = (char*)d_ws;
    const size_t SD = (size_t)SEQ * DM;   // 2M elements
    float*  qb  = (float*)ws;             // 8 MB
    float*  kb  = qb  + SD;               // 8 MB
    float*  eqb = kb  + SD;               // 8 MB
    float*  ekb = eqb + SD;               // 8 MB
    __bf16* mxT = (__bf16*)(ekb + SD);    // 4 MB
    float*  cA  = (float*)(mxT + SD);
    float*  sA  = cA + SEQ * NH;
    float*  lut = sA + SEQ * NH;
    float*  res = qb;                     // overlays qb (dead after attn)
    __bf16* vb  = (__bf16*)d_out;         // staged in d_out (dead after mixer)
    __bf16* ctx = (__bf16*)d_out;         // attn result, consumed by out_proj

    decay_kernel<<<8, 256, 0, stream>>>(lut);

    proj_f32<<<SEQ, 256, 0, stream>>>(hs, Wq,  bq,  qb);
    proj_f32<<<SEQ, 256, 0, stream>>>(hs, Wk,  bk,  kb);
    proj_f32<<<SEQ, 256, 0, stream>>>(hs, Weq, beq, eqb);
    proj_f32<<<SEQ, 256, 0, stream>>>(hs, Wek, bek, ekb);
    proj_bf <<<SEQ, 256, 0, stream>>>(hs, Wv,  bv,  vb);

    amp_naive<<<SEQ, 256, 0, stream>>>(hs, ampw, ampb, phw, phb, cA, sA);

    mixer_naive<<<dim3(SEQ, NH), 64, 0, stream>>>(vb, mixw, mixb, cA, sA, mxT);

    attn_f32<<<dim3(SEQ, NH), 256, 0, stream>>>(qb, kb, eqb, ekb, mxT, lut, ctx);

    outproj_naive<<<SEQ, 256, 0, stream>>>(ctx, Wo, bo, hs, res);

    lnorm_f32<<<SEQ, 256, 0, stream>>>(res, lng, lnb, out);
}